// Round 1
// baseline (961.244 us; speedup 1.0000x reference)
//
#include <hip/hip_runtime.h>
#include <hip/hip_cooperative_groups.h>

namespace cg = cooperative_groups;

#define B_  16
#define T_  2048
#define L_  128
#define M_  256
#define H_  512
#define F_  1024
#define EPS 1e-5f

// LDS: As[64][36] + Bs[64][68] = 6656 floats = 26624 B  (2 blocks/CU)
#define LDA_S 36
#define LDB_S 68
#define SMSZ (64 * LDA_S + 64 * LDB_S)

// ---------------------------------------------------------------------------
// A-operand load with source remap.
// amode: 0 = row-major(lda); 1 = gather x[b=r&15][T-1-(r>>4)][:];
//        2 = tree (row -> vin[((r>>4)<<5)+16+(r&15)]);
//        3 = rows 0..M-2 from A, row M-1 from Alast
// ---------------------------------------------------------------------------
__device__ __forceinline__ float4 load_a4(const float* __restrict__ A,
                                          const float* __restrict__ Alast,
                                          int M, int lda, int amode,
                                          int gr, int gk) {
    float4 av = make_float4(0.f, 0.f, 0.f, 0.f);
    if (gr < M) {
        const float* p;
        if (amode == 1)
            p = A + (long)((gr & 15) * T_ + (T_ - 1 - (gr >> 4))) * L_ + gk;
        else if (amode == 2)
            p = A + (long)(((gr >> 4) << 5) + 16 + (gr & 15)) * lda + gk;
        else if (amode == 3 && gr == M - 1)
            p = Alast + gk;
        else
            p = A + (long)gr * lda + gk;
        av = *(const float4*)p;
    }
    return av;
}

// ---------------------------------------------------------------------------
// 32x64 tile GEMM, BK=64, TM=2 TN=4, 256 threads, reg-prefetch pipeline.
// flags: 1 = +bias[c].  amode==2 epilogue adds Add[((r>>4)<<5)+(r&15)].
// ---------------------------------------------------------------------------
__device__ __forceinline__ void gemm_tile(
    float* sm,
    const float* __restrict__ A, const float* __restrict__ Alast,
    const float* __restrict__ Bm, const float* __restrict__ bias,
    const float* __restrict__ Add, float* __restrict__ C,
    int M, int K, int lda, int ldb, int ldc,
    int flags, int amode, int bx, int by)
{
    constexpr int BM = 32, BN = 64, BK = 64, TM = 2, TN = 4;
    float* As = sm;                    // [64][36] transposed A tile
    float* Bs = sm + BK * LDA_S;       // [64][68]
    const int tid = threadIdx.x;
    const int tx = tid & 15;           // BN/TN = 16
    const int ty = tid >> 4;           // 0..15
    const int row0 = by * BM, col0 = bx * BN;

    float4 pa[2], pb[4];
#pragma unroll
    for (int t = 0; t < 2; ++t) {
        int f = tid + t * 256;
        pa[t] = load_a4(A, Alast, M, lda, amode, row0 + (f >> 4), (f & 15) * 4);
    }
#pragma unroll
    for (int t = 0; t < 4; ++t) {
        int f = tid + t * 256;
        pb[t] = *(const float4*)(Bm + (long)(f >> 4) * ldb + col0 + (f & 15) * 4);
    }

    float acc[TM][TN] = {};

    for (int k0 = 0; k0 < K; k0 += BK) {
        __syncthreads();               // prior compute done reading LDS
#pragma unroll
        for (int t = 0; t < 2; ++t) {
            int f = tid + t * 256;
            int arow = f >> 4, kk = (f & 15) * 4;
            As[(kk + 0) * LDA_S + arow] = pa[t].x;
            As[(kk + 1) * LDA_S + arow] = pa[t].y;
            As[(kk + 2) * LDA_S + arow] = pa[t].z;
            As[(kk + 3) * LDA_S + arow] = pa[t].w;
        }
#pragma unroll
        for (int t = 0; t < 4; ++t) {
            int f = tid + t * 256;
            *(float4*)&Bs[(f >> 4) * LDB_S + (f & 15) * 4] = pb[t];
        }
        __syncthreads();
        int kn = k0 + BK;
        if (kn < K) {                  // prefetch next tiles; in flight during FMAs
#pragma unroll
            for (int t = 0; t < 2; ++t) {
                int f = tid + t * 256;
                pa[t] = load_a4(A, Alast, M, lda, amode, row0 + (f >> 4), kn + (f & 15) * 4);
            }
#pragma unroll
            for (int t = 0; t < 4; ++t) {
                int f = tid + t * 256;
                pb[t] = *(const float4*)(Bm + (long)(kn + (f >> 4)) * ldb + col0 + (f & 15) * 4);
            }
        }
#pragma unroll
        for (int kk = 0; kk < BK; ++kk) {
            float ra[TM], rb[TN];
#pragma unroll
            for (int i = 0; i < TM; ++i) ra[i] = As[kk * LDA_S + ty * TM + i];
#pragma unroll
            for (int j = 0; j < TN; ++j) rb[j] = Bs[kk * LDB_S + tx * TN + j];
#pragma unroll
            for (int i = 0; i < TM; ++i)
#pragma unroll
                for (int j = 0; j < TN; ++j)
                    acc[i][j] = fmaf(ra[i], rb[j], acc[i][j]);
        }
    }

#pragma unroll
    for (int i = 0; i < TM; ++i) {
        int r = row0 + ty * TM + i;
        if (r >= M) continue;
#pragma unroll
        for (int j = 0; j < TN; ++j) {
            int c = col0 + tx * TN + j;
            float v = acc[i][j];
            if (flags & 1) v += bias[c];
            if (amode == 2) v += Add[(long)(((r >> 4) << 5) + (r & 15)) * ldc + c];
            C[(long)r * ldc + c] = v;
        }
    }
}

// Dual-job kernel (FALLBACK path): blocks [0,nA) run job A; blocks [nA, ...)
// compute SqOut = SqL @ SqR (512x512x512) for the A-power chain.
__global__ __launch_bounds__(256) void dual(
    const float* A, const float* Alast, const float* Bm, const float* bias,
    const float* Add, float* C, int M, int K, int lda, int ldb, int ldc,
    int flags, int amode, int nbxA, int nA,
    const float* SqL, const float* SqR, float* SqOut)
{
    __shared__ float sm[SMSZ];
    int j = blockIdx.x;
    if (j < nA)
        gemm_tile(sm, A, Alast, Bm, bias, Add, C, M, K, lda, ldb, ldc,
                  flags, amode, j % nbxA, j / nbxA);
    else {
        int s = j - nA;
        gemm_tile(sm, SqL, nullptr, SqR, nullptr, nullptr, SqOut,
                  H_, H_, H_, H_, H_, 0, 0, s % 8, s / 8);
    }
}

// ---------------------------------------------------------------------------
// Tail split-K GEMM: BM=16, BN=64, BK=64, 256 threads, 4 outputs/thread.
// MODE 0: z-GEMM  A = [V1nodes1..3 | x_last] (K=1664), B = [P32;P64;P96;Wr]
// MODE 1: MLP1    A = zn (16x512),  B = W1 (512x1024)
// MODE 2: MLP2    A = hid (16x1024), B = W2 (1024x512)
// Writes partials: parts[kc][16][LDC], kc = jb / nbx.
// ---------------------------------------------------------------------------
#define TLDA 20
#define TLDB 68
#define TSM (64 * TLDA + 64 * TLDB)

template <int MODE>
__device__ __forceinline__ float4 tail_a4(const float* __restrict__ Asrc,
                                          const float* __restrict__ x,
                                          int b, int gk) {
    if (MODE == 0) {
        int seg = gk >> 9;
        if (seg < 3)
            return *(const float4*)(Asrc + (long)((seg + 1) * 16 + b) * H_ + (gk & 511));
        return *(const float4*)(x + ((long)b * T_ + (T_ - 1)) * L_ + (gk - 1536));
    } else if (MODE == 1) {
        return *(const float4*)(Asrc + (long)b * H_ + gk);
    } else {
        return *(const float4*)(Asrc + (long)b * F_ + gk);
    }
}

template <int MODE>
__device__ __forceinline__ float4 tail_b4(const float* __restrict__ P32,
                                          const float* __restrict__ P64,
                                          const float* __restrict__ P96,
                                          const float* __restrict__ WrB,
                                          int kr, int c) {
    if (MODE == 0) {
        const float* p;
        if (kr < 512)       p = P32 + (long)kr * H_;
        else if (kr < 1024) p = P64 + (long)(kr - 512) * H_;
        else if (kr < 1536) p = P96 + (long)(kr - 1024) * H_;
        else                p = WrB + (long)(kr - 1536) * H_;
        return *(const float4*)(p + c);
    } else if (MODE == 1) {
        return *(const float4*)(WrB + (long)kr * F_ + c);
    } else {
        return *(const float4*)(WrB + (long)kr * H_ + c);
    }
}

template <int MODE>
__device__ __forceinline__ void tail_job(
    float* sm,
    const float* __restrict__ Asrc, const float* __restrict__ x,
    const float* __restrict__ P32, const float* __restrict__ P64,
    const float* __restrict__ P96, const float* __restrict__ WrB,
    float* __restrict__ parts, int nbx, int kLen, int jb)
{
    constexpr int LDC = (MODE == 1) ? F_ : H_;
    float* As = sm;                    // [64][20] transposed (A[k][row])
    float* Bs = sm + 64 * TLDA;        // [64][68]
    const int tid = threadIdx.x;
    const int tx = tid & 15, ty = tid >> 4;      // ty = row 0..15
    const int kc = jb / nbx;
    const int col0 = (jb % nbx) * 64;
    const int kOff = kc * kLen;

    float4 pa, pb[4];
    {
        int gk = kOff + (tid & 15) * 4;
        pa = tail_a4<MODE>(Asrc, x, tid >> 4, gk);
#pragma unroll
        for (int t = 0; t < 4; ++t) {
            int f = tid + t * 256;
            pb[t] = tail_b4<MODE>(P32, P64, P96, WrB, kOff + (f >> 4), col0 + (f & 15) * 4);
        }
    }

    float acc[4] = {};
    for (int k0 = kOff; k0 < kOff + kLen; k0 += 64) {
        __syncthreads();
        {
            int arow = tid >> 4, kk = (tid & 15) * 4;
            As[(kk + 0) * TLDA + arow] = pa.x;
            As[(kk + 1) * TLDA + arow] = pa.y;
            As[(kk + 2) * TLDA + arow] = pa.z;
            As[(kk + 3) * TLDA + arow] = pa.w;
        }
#pragma unroll
        for (int t = 0; t < 4; ++t) {
            int f = tid + t * 256;
            *(float4*)&Bs[(f >> 4) * TLDB + (f & 15) * 4] = pb[t];
        }
        __syncthreads();
        int kn = k0 + 64;
        if (kn < kOff + kLen) {
            pa = tail_a4<MODE>(Asrc, x, tid >> 4, kn + (tid & 15) * 4);
#pragma unroll
            for (int t = 0; t < 4; ++t) {
                int f = tid + t * 256;
                pb[t] = tail_b4<MODE>(P32, P64, P96, WrB, kn + (f >> 4), col0 + (f & 15) * 4);
            }
        }
#pragma unroll
        for (int kk = 0; kk < 64; ++kk) {
            float ra = As[kk * TLDA + ty];
            float4 rb = *(float4*)&Bs[kk * TLDB + tx * 4];
            acc[0] = fmaf(ra, rb.x, acc[0]);
            acc[1] = fmaf(ra, rb.y, acc[1]);
            acc[2] = fmaf(ra, rb.z, acc[2]);
            acc[3] = fmaf(ra, rb.w, acc[3]);
        }
    }

    float* dst = parts + (long)kc * 16 * LDC + (long)ty * LDC + col0 + tx * 4;
    *(float4*)dst = make_float4(acc[0], acc[1], acc[2], acc[3]);
}

template <int MODE>
__global__ __launch_bounds__(256) void tailgemm(
    const float* __restrict__ Asrc, const float* __restrict__ x,
    const float* __restrict__ P32, const float* __restrict__ P64,
    const float* __restrict__ P96, const float* __restrict__ WrB,
    float* __restrict__ parts, int nbx, int kLen)
{
    __shared__ float sm[TSM];
    tail_job<MODE>(sm, Asrc, x, P32, P64, P96, WrB, parts, nbx, kLen, blockIdx.x);
}

// z = node0 + br + sum(zparts); LayerNorm -> zn.  (job b = batch row)
__device__ __forceinline__ void zln_job(
    float* red, const float* __restrict__ V1, const float* __restrict__ zparts,
    const float* __restrict__ br, const float* __restrict__ lng,
    const float* __restrict__ lnb, float* __restrict__ zn, int b)
{
    const int tid = threadIdx.x;
    float z[2];
#pragma unroll
    for (int jj = 0; jj < 2; ++jj) {
        int c = tid + jj * 256;
        float s = V1[(long)b * H_ + c] + br[c];      // node0 row
#pragma unroll
        for (int kc = 0; kc < 13; ++kc)
            s += zparts[(long)kc * 16 * H_ + (long)b * H_ + c];
        z[jj] = s;
    }
    float s1 = z[0] + z[1];
    float s2 = z[0] * z[0] + z[1] * z[1];
#pragma unroll
    for (int off = 32; off > 0; off >>= 1) {
        s1 += __shfl_down(s1, off, 64);
        s2 += __shfl_down(s2, off, 64);
    }
    int wid = tid >> 6, lane = tid & 63;
    __syncthreads();
    if (lane == 0) { red[wid] = s1; red[4 + wid] = s2; }
    __syncthreads();
    float S1 = red[0] + red[1] + red[2] + red[3];
    float S2 = red[4] + red[5] + red[6] + red[7];
    float mu  = S1 * (1.0f / H_);
    float var = S2 * (1.0f / H_) - mu * mu;
    float rs  = rsqrtf(var + EPS);
#pragma unroll
    for (int jj = 0; jj < 2; ++jj) {
        int c = tid + jj * 256;
        zn[(long)b * H_ + c] = (z[jj] - mu) * rs * lng[c] + lnb[c];
    }
}

__global__ __launch_bounds__(256) void zlnred(
    const float* __restrict__ V1, const float* __restrict__ zparts,
    const float* __restrict__ br, const float* __restrict__ lng,
    const float* __restrict__ lnb, float* __restrict__ zn)
{
    __shared__ float red[8];
    zln_job(red, V1, zparts, br, lng, lnb, zn, blockIdx.x);
}

// hid = relu(b1 + sum_{kc<4} h1p[kc])
__device__ __forceinline__ void hred_job(const float* __restrict__ h1p,
                                         const float* __restrict__ b1,
                                         float* __restrict__ hid, int j)
{
    int b = j >> 2;
    int c = (j & 3) * 256 + threadIdx.x;
    float s = b1[c];
#pragma unroll
    for (int kc = 0; kc < 4; ++kc)
        s += h1p[(long)kc * 16 * F_ + (long)b * F_ + c];
    hid[(long)b * F_ + c] = fmaxf(s, 0.f);
}

__global__ __launch_bounds__(256) void hred(
    const float* __restrict__ h1p, const float* __restrict__ b1,
    float* __restrict__ hid)
{
    hred_job(h1p, b1, hid, blockIdx.x);
}

// out = b2 + sum_{kc<8} op[kc]
__device__ __forceinline__ void ored_job(const float* __restrict__ op,
                                         const float* __restrict__ b2,
                                         float* __restrict__ out, int j)
{
    int b = j >> 1;
    int c = (j & 1) * 256 + threadIdx.x;
    float s = b2[c];
#pragma unroll
    for (int kc = 0; kc < 8; ++kc)
        s += op[(long)kc * 16 * H_ + (long)b * H_ + c];
    out[(long)b * H_ + c] = s;
}

__global__ __launch_bounds__(256) void ored(
    const float* __restrict__ op, const float* __restrict__ b2,
    float* __restrict__ out)
{
    ored_job(op, b2, out, blockIdx.x);
}

// ---------------------------------------------------------------------------
// Persistent cooperative mega-kernel: the entire 13-stage pipeline with
// grid.sync() between stages instead of kernel boundaries.
// 512 blocks x 256 threads, 2 blocks/CU co-resident (LDS 26.6KB x2, VGPR<=256).
// ---------------------------------------------------------------------------
__global__ __launch_bounds__(256, 2) void mega(
    const float* __restrict__ x, const float* __restrict__ We,
    const float* __restrict__ be, const float* __restrict__ Wb,
    const float* __restrict__ Amat, const float* __restrict__ Wr,
    const float* __restrict__ br, const float* __restrict__ lng,
    const float* __restrict__ lnb, const float* __restrict__ W1,
    const float* __restrict__ b1, const float* __restrict__ W2,
    const float* __restrict__ b2, float* __restrict__ out,
    float* __restrict__ ws)
{
    __shared__ float sm[SMSZ];
    float* Wc  = ws;                         // 129 x 512
    float* V0  = Wc + 129 * H_;              // 2048 x 512
    float* V1  = V0 + 2048 * H_;             // 1024 x 512
    float* P2  = V1 + 1024 * H_;             // A^2
    float* P4  = P2 + H_ * H_;               // A^4
    float* P8  = P4 + H_ * H_;               // A^8
    float* P16 = P8 + H_ * H_;               // A^16
    float* P32 = P16 + H_ * H_;              // A^32
    float* P64 = P32 + H_ * H_;              // A^64
    float* P96 = P64 + H_ * H_;              // A^96
    float* zn  = P96 + H_ * H_;              // 16 x 512
    float* hid = zn + B_ * H_;               // 16 x 1024
    float* zp  = hid + B_ * F_;              // 13 x 16 x 512
    float* h1p = zp + 13 * B_ * H_;          // 4 x 16 x 1024
    float* op  = h1p + 4 * B_ * F_;          // 8 x 16 x 512

    cg::grid_group gg = cg::this_grid();
    const int bid = blockIdx.x;
    const int NB  = gridDim.x;

    // S0: Wc = [We;be]@Wb (40 jobs) || A^2 (128 jobs)
    for (int j = bid; j < 168; j += NB) {
        if (j < 40)
            gemm_tile(sm, We, be, Wb, nullptr, nullptr, Wc,
                      129, M_, M_, H_, H_, 0, 3, j & 7, j >> 3);
        else {
            int s = j - 40;
            gemm_tile(sm, Amat, nullptr, Amat, nullptr, nullptr, P2,
                      H_, H_, H_, H_, H_, 0, 0, s & 7, s >> 3);
        }
    }
    gg.sync();

    // S1: V0 = gather(x)@Wc + bc (512 jobs) || A^4 (128)
    for (int j = bid; j < 640; j += NB) {
        if (j < 512)
            gemm_tile(sm, x, nullptr, Wc, Wc + 128 * H_, nullptr, V0,
                      2048, L_, L_, H_, H_, 1, 1, j & 7, j >> 3);
        else {
            int s = j - 512;
            gemm_tile(sm, P2, nullptr, P2, nullptr, nullptr, P4,
                      H_, H_, H_, H_, H_, 0, 0, s & 7, s >> 3);
        }
    }
    gg.sync();

    // S2: tree L1: V1 = comb(V0, A), 1024 rows (256) || A^8 (128)
    for (int j = bid; j < 384; j += NB) {
        if (j < 256)
            gemm_tile(sm, V0, nullptr, Amat, nullptr, V0, V1,
                      1024, H_, H_, H_, H_, 0, 2, j & 7, j >> 3);
        else {
            int s = j - 256;
            gemm_tile(sm, P4, nullptr, P4, nullptr, nullptr, P8,
                      H_, H_, H_, H_, H_, 0, 0, s & 7, s >> 3);
        }
    }
    gg.sync();

    // S3: tree L2: V0 = comb(V1, A^2), 512 rows (128) || A^16 (128)
    for (int j = bid; j < 256; j += NB) {
        if (j < 128)
            gemm_tile(sm, V1, nullptr, P2, nullptr, V1, V0,
                      512, H_, H_, H_, H_, 0, 2, j & 7, j >> 3);
        else {
            int s = j - 128;
            gemm_tile(sm, P8, nullptr, P8, nullptr, nullptr, P16,
                      H_, H_, H_, H_, H_, 0, 0, s & 7, s >> 3);
        }
    }
    gg.sync();

    // S4: tree L3: V1 = comb(V0, A^4), 256 rows (64) || A^32 (128)
    for (int j = bid; j < 192; j += NB) {
        if (j < 64)
            gemm_tile(sm, V0, nullptr, P4, nullptr, V0, V1,
                      256, H_, H_, H_, H_, 0, 2, j & 7, j >> 3);
        else {
            int s = j - 64;
            gemm_tile(sm, P16, nullptr, P16, nullptr, nullptr, P32,
                      H_, H_, H_, H_, H_, 0, 0, s & 7, s >> 3);
        }
    }
    gg.sync();

    // S5: tree L4: V0 = comb(V1, A^8), 128 rows (32) || A^64 (128)
    for (int j = bid; j < 160; j += NB) {
        if (j < 32)
            gemm_tile(sm, V1, nullptr, P8, nullptr, V1, V0,
                      128, H_, H_, H_, H_, 0, 2, j & 7, j >> 3);
        else {
            int s = j - 32;
            gemm_tile(sm, P32, nullptr, P32, nullptr, nullptr, P64,
                      H_, H_, H_, H_, H_, 0, 0, s & 7, s >> 3);
        }
    }
    gg.sync();

    // S6: tree L5: V1 = comb(V0, A^16), 64 rows (16) || A^96 = A^32*A^64 (128)
    for (int j = bid; j < 144; j += NB) {
        if (j < 16)
            gemm_tile(sm, V0, nullptr, P16, nullptr, V0, V1,
                      64, H_, H_, H_, H_, 0, 2, j & 7, j >> 3);
        else {
            int s = j - 16;
            gemm_tile(sm, P32, nullptr, P64, nullptr, nullptr, P96,
                      H_, H_, H_, H_, H_, 0, 0, s & 7, s >> 3);
        }
    }
    gg.sync();

    // S7: z-partials (K=1664, 13 chunks x 8 col tiles = 104 jobs)
    for (int j = bid; j < 104; j += NB)
        tail_job<0>(sm, V1, x, P32, P64, P96, Wr, zp, 8, 128, j);
    gg.sync();

    // S7b: z reduce + LayerNorm -> zn (16 jobs)
    for (int j = bid; j < 16; j += NB)
        zln_job(sm, V1, zp, br, lng, lnb, zn, j);
    gg.sync();

    // S8: MLP1 partials (64 jobs)
    for (int j = bid; j < 64; j += NB)
        tail_job<1>(sm, zn, nullptr, nullptr, nullptr, nullptr, W1, h1p, 16, 128, j);
    gg.sync();

    // S8b: relu-reduce -> hid (64 jobs)
    for (int j = bid; j < 64; j += NB)
        hred_job(h1p, b1, hid, j);
    gg.sync();

    // S9: MLP2 partials (64 jobs)
    for (int j = bid; j < 64; j += NB)
        tail_job<2>(sm, hid, nullptr, nullptr, nullptr, nullptr, W2, op, 8, 128, j);
    gg.sync();

    // S9b: reduce -> out (32 jobs)
    for (int j = bid; j < 32; j += NB)
        ored_job(op, b2, out, j);
}

// ---------------------------------------------------------------------------
extern "C" void kernel_launch(void* const* d_in, const int* in_sizes, int n_in,
                              void* d_out, int out_size, void* d_ws, size_t ws_size,
                              hipStream_t stream) {
    const float* x    = (const float*)d_in[0];
    const float* We   = (const float*)d_in[1];
    const float* be   = (const float*)d_in[2];
    const float* Wb   = (const float*)d_in[3];
    const float* Amat = (const float*)d_in[4];
    const float* Wr   = (const float*)d_in[5];
    const float* br   = (const float*)d_in[6];
    const float* lng  = (const float*)d_in[7];
    const float* lnb  = (const float*)d_in[8];
    const float* W1   = (const float*)d_in[9];
    const float* b1   = (const float*)d_in[10];
    const float* W2   = (const float*)d_in[11];
    const float* b2   = (const float*)d_in[12];
    float* out = (float*)d_out;
    float* ws  = (float*)d_ws;

    // ---- cooperative mega-kernel path ----
    void* kargs[] = {
        (void*)&x,   (void*)&We,  (void*)&be,  (void*)&Wb,  (void*)&Amat,
        (void*)&Wr,  (void*)&br,  (void*)&lng, (void*)&lnb, (void*)&W1,
        (void*)&b1,  (void*)&W2,  (void*)&b2,  (void*)&out, (void*)&ws };

    hipError_t e = hipLaunchCooperativeKernel((const void*)mega, dim3(512),
                                              dim3(256), kargs, 0, stream);
    if (e != hipSuccess) {
        (void)hipGetLastError();
        e = hipLaunchCooperativeKernel((const void*)mega, dim3(256),
                                       dim3(256), kargs, 0, stream);
    }
    if (e == hipSuccess) return;
    (void)hipGetLastError();

    // ---- fallback: original 13-launch sequence ----
    float* Wc  = ws;
    float* V0  = Wc + 129 * H_;
    float* V1  = V0 + 2048 * H_;
    float* P2  = V1 + 1024 * H_;
    float* P4  = P2 + H_ * H_;
    float* P8  = P4 + H_ * H_;
    float* P16 = P8 + H_ * H_;
    float* P32 = P16 + H_ * H_;
    float* P64 = P32 + H_ * H_;
    float* P96 = P64 + H_ * H_;
    float* zn  = P96 + H_ * H_;
    float* hid = zn + B_ * H_;
    float* zp  = hid + B_ * F_;
    float* h1p = zp + 13 * B_ * H_;
    float* op  = h1p + 4 * B_ * F_;

    dual<<<168, 256, 0, stream>>>(We, be, Wb, nullptr, nullptr, Wc,
                                  129, M_, M_, H_, H_, 0, 3, 8, 40,
                                  Amat, Amat, P2);
    dual<<<640, 256, 0, stream>>>(x, nullptr, Wc, Wc + 128 * H_, nullptr, V0,
                                  2048, L_, L_, H_, H_, 1, 1, 8, 512,
                                  P2, P2, P4);
    dual<<<384, 256, 0, stream>>>(V0, nullptr, Amat, nullptr, V0, V1,
                                  1024, H_, H_, H_, H_, 0, 2, 8, 256,
                                  P4, P4, P8);
    dual<<<256, 256, 0, stream>>>(V1, nullptr, P2, nullptr, V1, V0,
                                  512, H_, H_, H_, H_, 0, 2, 8, 128,
                                  P8, P8, P16);
    dual<<<192, 256, 0, stream>>>(V0, nullptr, P4, nullptr, V0, V1,
                                  256, H_, H_, H_, H_, 0, 2, 8, 64,
                                  P16, P16, P32);
    dual<<<160, 256, 0, stream>>>(V1, nullptr, P8, nullptr, V1, V0,
                                  128, H_, H_, H_, H_, 0, 2, 8, 32,
                                  P32, P32, P64);
    dual<<<144, 256, 0, stream>>>(V0, nullptr, P16, nullptr, V0, V1,
                                  64, H_, H_, H_, H_, 0, 2, 8, 16,
                                  P32, P64, P96);
    tailgemm<0><<<104, 256, 0, stream>>>(V1, x, P32, P64, P96, Wr, zp, 8, 128);
    zlnred<<<16, 256, 0, stream>>>(V1, zp, br, lng, lnb, zn);
    tailgemm<1><<<64, 256, 0, stream>>>(zn, nullptr, nullptr, nullptr, nullptr,
                                        W1, h1p, 16, 128);
    hred<<<64, 256, 0, stream>>>(h1p, b1, hid);
    tailgemm<2><<<64, 256, 0, stream>>>(hid, nullptr, nullptr, nullptr, nullptr,
                                        W2, op, 8, 128);
    ored<<<32, 256, 0, stream>>>(op, b2, out);
}